// Round 3
// baseline (496.352 us; speedup 1.0000x reference)
//
#include <hip/hip_runtime.h>

#define B_ 32
#define C_ 512
#define HW_ 3136
#define KF_ 512
#define KM_ 48
#define NCL_ 5

typedef __attribute__((ext_vector_type(8))) short short8;
typedef __attribute__((ext_vector_type(4))) short short4v;
typedef __attribute__((ext_vector_type(4))) float floatx4;
typedef unsigned int u32;
typedef u32 __attribute__((address_space(1))) gu32;
typedef u32 __attribute__((address_space(3))) lu32;

__device__ __forceinline__ unsigned short f2bf(float f) {
    union { float f; unsigned u; } v; v.f = f;
    unsigned r = v.u + 0x7FFFu + ((v.u >> 16) & 1u);
    return (unsigned short)(r >> 16);
}
__device__ __forceinline__ float bf2f(unsigned short u) {
    union { unsigned u; float f; } v; v.u = ((unsigned)u) << 16;
    return v.f;
}
__device__ __forceinline__ void gl2lds16(const unsigned short* g, unsigned short* l) {
    __builtin_amdgcn_global_load_lds((const gu32*)g, (lu32*)l, 16, 0, 0);
}

// ---- K0: normalize conv weights -> bf16 wn; clutter -> ck (clip + L1 norm)
__global__ __launch_bounds__(64) void prep_kernel(const float* __restrict__ w,
                                                  const float* __restrict__ cl,
                                                  unsigned short* __restrict__ wn,
                                                  float* __restrict__ ck) {
    int bid = blockIdx.x, t = threadIdx.x;
    if (bid < KF_) {
        const float* row = w + (size_t)bid * C_;
        float ss = 0.f;
        float x[8];
#pragma unroll
        for (int j = 0; j < 8; ++j) { x[j] = row[t * 8 + j]; ss += x[j] * x[j]; }
        for (int m = 32; m >= 1; m >>= 1) ss += __shfl_xor(ss, m);
        float inv = 1.f / sqrtf(ss);
#pragma unroll
        for (int j = 0; j < 8; ++j) wn[(size_t)bid * C_ + t * 8 + j] = f2bf(x[j] * inv);
    } else {
        int n = bid - KF_;
        if (n >= NCL_) return;
        const float* row = cl + (size_t)n * KF_;
        float s = 0.f;
        float v[8];
#pragma unroll
        for (int j = 0; j < 8; ++j) {
            float x = row[t * 8 + j];
            x = fminf(fmaxf(x, 0.f), 1.f);
            v[j] = x; s += x;
        }
        for (int m = 32; m >= 1; m >>= 1) s += __shfl_xor(s, m);
        float inv = 1.f / fmaxf(s, 1e-12f);
#pragma unroll
        for (int j = 0; j < 8; ++j) ck[(size_t)n * KF_ + t * 8 + j] = v[j] * inv;
    }
}

// ---- K1: streaming pass: vgg -> xnt (raw bf16, [b*HW+p][c]), invn, vgg copy
__global__ __launch_bounds__(512) void xprep_kernel(const float* __restrict__ vgg,
                                                    unsigned short* __restrict__ xnt,
                                                    float* __restrict__ invn,
                                                    float* __restrict__ out_vgg,
                                                    int write_vgg) {
    int pt = blockIdx.x, b = blockIdx.y;
    int tid = threadIdx.x;
    int px = tid & 63, cq = tid >> 6;
    __shared__ __align__(16) unsigned short tile[64][512];
    __shared__ float ssp[8][64];
    const float* vcol = vgg + (size_t)b * C_ * HW_ + pt * 64 + px;
    float* ovcol = out_vgg + (size_t)b * C_ * HW_ + pt * 64 + px;

    float ss = 0.f;
#pragma unroll
    for (int j = 0; j < 16; ++j) {
        int c0 = cq * 64 + j * 4;
        float x0 = vcol[(size_t)(c0 + 0) * HW_];
        float x1 = vcol[(size_t)(c0 + 1) * HW_];
        float x2 = vcol[(size_t)(c0 + 2) * HW_];
        float x3 = vcol[(size_t)(c0 + 3) * HW_];
        ss += x0 * x0 + x1 * x1 + x2 * x2 + x3 * x3;
        short4v pk;
        pk[0] = (short)f2bf(x0); pk[1] = (short)f2bf(x1);
        pk[2] = (short)f2bf(x2); pk[3] = (short)f2bf(x3);
        *(short4v*)&tile[px][c0] = pk;
        if (write_vgg) {
            ovcol[(size_t)(c0 + 0) * HW_] = x0;
            ovcol[(size_t)(c0 + 1) * HW_] = x1;
            ovcol[(size_t)(c0 + 2) * HW_] = x2;
            ovcol[(size_t)(c0 + 3) * HW_] = x3;
        }
    }
    ssp[cq][px] = ss;
    __syncthreads();
    if (tid < 64) {
        float s = 0.f;
#pragma unroll
        for (int q = 0; q < 8; ++q) s += ssp[q][tid];
        float n = sqrtf(s);
        invn[(size_t)b * HW_ + pt * 64 + tid] = (n == 0.f) ? 1.f : 1.f / n;
    }
    __syncthreads();
    int row = tid >> 3, ch = tid & 7;
    unsigned short* orow = xnt + ((size_t)b * HW_ + pt * 64 + row) * 512;
#pragma unroll
    for (int j = 0; j < 8; ++j) {
        int c8 = (ch + 8 * j) * 8;
        *(short8*)(orow + c8) = *(const short8*)&tile[row][c8];
    }
}

// ---- K2: flat GEMM act = exp(30 * (xnt . wn) * invn) (m97 structure) + bg partials
// grid (784 px-tiles of 128, 4 filter-tiles of 128), 256 threads (4 waves).
__global__ __launch_bounds__(256) void gemm_act_kernel(const unsigned short* __restrict__ xnt,
                                                       const unsigned short* __restrict__ wn,
                                                       const float* __restrict__ invn,
                                                       const float* __restrict__ ck,
                                                       unsigned short* __restrict__ act,
                                                       float* __restrict__ bgacc) {
    int pt = blockIdx.x, ft = blockIdx.y;
    int tid = threadIdx.x, lane = tid & 63, w = tid >> 6;
    int wm = w & 1, wq = w >> 1;
    __shared__ __align__(16) unsigned short a_lds[128 * 64];
    __shared__ __align__(16) unsigned short b_lds[128 * 64];
    __shared__ float ck_l[NCL_ * KF_];
    __shared__ float inv_l[128];
    __shared__ float bga_l[128 * NCL_];

    for (int i = tid; i < NCL_ * KF_; i += 256) ck_l[i] = ck[i];
    if (tid < 128) inv_l[tid] = invn[(size_t)pt * 128 + tid];
    for (int i = tid; i < 128 * NCL_; i += 256) bga_l[i] = 0.f;

    const unsigned short* ga = wn + ((size_t)(ft * 128) + (tid >> 3)) * 512 + (tid & 7) * 8;
    const unsigned short* gb = xnt + ((size_t)pt * 128 + (tid >> 3)) * 512 + (tid & 7) * 8;
    unsigned short* la = a_lds + (tid >> 3) * 64 + (tid & 7) * 8;
    unsigned short* lb = b_lds + (tid >> 3) * 64 + (tid & 7) * 8;

    floatx4 acc[4][4] = {};
    for (int ks = 0; ks < 8; ++ks) {
#pragma unroll
        for (int s = 0; s < 4; ++s) {
            gl2lds16(ga + (size_t)s * 32 * 512 + ks * 64, la + s * 32 * 64);
            gl2lds16(gb + (size_t)s * 32 * 512 + ks * 64, lb + s * 32 * 64);
        }
        __syncthreads();
#pragma unroll
        for (int k2 = 0; k2 < 2; ++k2) {
            short8 af[4], bf[4];
#pragma unroll
            for (int i = 0; i < 4; ++i) {
                af[i] = *(const short8*)&a_lds[(wm * 64 + i * 16 + (lane & 15)) * 64 + k2 * 32 + (lane >> 4) * 8];
                bf[i] = *(const short8*)&b_lds[(wq * 64 + i * 16 + (lane & 15)) * 64 + k2 * 32 + (lane >> 4) * 8];
            }
#pragma unroll
            for (int mi = 0; mi < 4; ++mi)
#pragma unroll
                for (int ni = 0; ni < 4; ++ni)
                    acc[mi][ni] = __builtin_amdgcn_mfma_f32_16x16x32_bf16(af[mi], bf[ni], acc[mi][ni], 0, 0, 0);
        }
        __syncthreads();
    }

    // epilogue: scale by invn, exp, store bf16 act (k-contiguous), bg partials
#pragma unroll
    for (int ni = 0; ni < 4; ++ni) {
        int px_l = wq * 64 + ni * 16 + (lane & 15);
        float inv = inv_l[px_l];
        size_t row_g = (size_t)pt * 128 + px_l;
        float bp[NCL_] = {0.f, 0.f, 0.f, 0.f, 0.f};
#pragma unroll
        for (int mi = 0; mi < 4; ++mi) {
            int f_g = ft * 128 + wm * 64 + mi * 16 + (lane >> 4) * 4;
            short4v pk;
            float av[4];
#pragma unroll
            for (int r = 0; r < 4; ++r) {
                float cv = acc[mi][ni][r] * inv;
                float a = cv > 0.f ? __expf(30.f * cv) : 0.f;
                av[r] = a;
                pk[r] = (short)f2bf(a);
            }
            *(short4v*)(act + row_g * 512 + f_g) = pk;
#pragma unroll
            for (int n = 0; n < NCL_; ++n)
                bp[n] += av[0] * ck_l[n * KF_ + f_g] + av[1] * ck_l[n * KF_ + f_g + 1] +
                         av[2] * ck_l[n * KF_ + f_g + 2] + av[3] * ck_l[n * KF_ + f_g + 3];
        }
#pragma unroll
        for (int n = 0; n < NCL_; ++n) {
            float v = bp[n];
            v += __shfl_xor(v, 16);
            v += __shfl_xor(v, 32);
            if ((lane >> 4) == 0) atomicAdd(&bga_l[px_l * NCL_ + n], v);
        }
    }
    __syncthreads();
    if (tid < 128) {
        size_t row_g = (size_t)pt * 128 + tid;
#pragma unroll
        for (int n = 0; n < NCL_; ++n)
            atomicAdd(&bgacc[row_g * 8 + n], bga_l[tid * NCL_ + n]);
    }
}

// ---- K4: fg GEMM + mm L1-norm + max(fg_log, background) + reduce over pixels
__global__ __launch_bounds__(512, 4) void fg_kernel(const unsigned short* __restrict__ act,
                                                    const float* __restrict__ mm,
                                                    const float* __restrict__ bgacc,
                                                    float* __restrict__ pm) {
    int p0 = blockIdx.x * 16;
    int mt = blockIdx.y;
    int tid = threadIdx.x;
    int lane = tid & 63, wid = tid >> 6;

    __shared__ __align__(16) unsigned short actl[4 * 4224];
    __shared__ __align__(16) unsigned short mml[4 * 2176];
    __shared__ float csum_s[16 * 16];  // [m][p]
    __shared__ float pms[16 * 32];     // [m][b]
    __shared__ float bgs[32 * 16];     // [b][p]

    if (tid < 256) csum_s[tid] = 0.f;
    pms[tid] = 0.f;
    {
        int bb = tid >> 4, pp = tid & 15;
        const float* bga = bgacc + ((size_t)bb * HW_ + p0 + pp) * 8;
        float mx = -1e30f;
#pragma unroll
        for (int n = 0; n < NCL_; ++n) mx = fmaxf(mx, logf(bga[n] * 0.6f + 1e-10f));
        bgs[tid] = mx;
    }

    int akg = tid & 3, ap = (tid >> 2) & 15, ab0 = tid >> 6;
    int mmm = tid >> 5, mkq = (tid >> 2) & 7, mpq = tid & 3;
    const float* mbase = mm + ((size_t)(mt * 16 + mmm) * KF_ + mkq * 4) * HW_ + p0 + mpq * 4;

    const short8* fA[2];
    const short8* fB[2][2];
#pragma unroll
    for (int e = 0; e < 2; ++e) {
        int pp = wid * 2 + e;
        fA[e] = (const short8*)&mml[(lane >> 4) * 2176 + pp * 136 + (lane & 15) * 8];
#pragma unroll
        for (int bf = 0; bf < 2; ++bf)
            fB[e][bf] = (const short8*)&actl[(lane >> 4) * 4224 + pp * 264 + (bf * 16 + (lane & 15)) * 8];
    }

    floatx4 acc[2][2] = {};
    float csr[4] = {};

    short8 areg[4];
    floatx4 mreg[4];
#pragma unroll
    for (int j = 0; j < 4; ++j)
        areg[j] = *(const short8*)(act + ((size_t)(ab0 + j * 8) * HW_ + p0 + ap) * KF_ + akg * 8);
#pragma unroll
    for (int kk = 0; kk < 4; ++kk)
        mreg[kk] = *(const floatx4*)(mbase + (size_t)kk * HW_);

    for (int ch = 0; ch < 16; ++ch) {
        __syncthreads();
#pragma unroll
        for (int j = 0; j < 4; ++j)
            *(short8*)&actl[akg * 4224 + ap * 264 + (ab0 + j * 8) * 8] = areg[j];
#pragma unroll
        for (int i = 0; i < 4; ++i) {
            float c0 = fminf(fmaxf(mreg[0][i], 0.f), 1.f);
            float c1 = fminf(fmaxf(mreg[1][i], 0.f), 1.f);
            float c2 = fminf(fmaxf(mreg[2][i], 0.f), 1.f);
            float c3 = fminf(fmaxf(mreg[3][i], 0.f), 1.f);
            csr[i] += c0 + c1 + c2 + c3;
            short4v pk;
            pk[0] = (short)f2bf(c0); pk[1] = (short)f2bf(c1);
            pk[2] = (short)f2bf(c2); pk[3] = (short)f2bf(c3);
            *(short4v*)&mml[(mkq >> 1) * 2176 + (mpq * 4 + i) * 136 + mmm * 8 + (mkq & 1) * 4] = pk;
        }
        if (ch < 15) {
            int k0 = (ch + 1) * 32;
#pragma unroll
            for (int j = 0; j < 4; ++j)
                areg[j] = *(const short8*)(act + ((size_t)(ab0 + j * 8) * HW_ + p0 + ap) * KF_ + k0 + akg * 8);
#pragma unroll
            for (int kk = 0; kk < 4; ++kk)
                mreg[kk] = *(const floatx4*)(mbase + (size_t)(k0 + kk) * HW_);
        }
        __syncthreads();
#pragma unroll
        for (int e = 0; e < 2; ++e) {
            short8 af = *fA[e];
            short8 b0 = *fB[e][0];
            short8 b1 = *fB[e][1];
            acc[e][0] = __builtin_amdgcn_mfma_f32_16x16x32_bf16(af, b0, acc[e][0], 0, 0, 0);
            acc[e][1] = __builtin_amdgcn_mfma_f32_16x16x32_bf16(af, b1, acc[e][1], 0, 0, 0);
        }
    }

#pragma unroll
    for (int i = 0; i < 4; ++i)
        atomicAdd(&csum_s[mmm * 16 + mpq * 4 + i], csr[i]);
    __syncthreads();

#pragma unroll
    for (int e = 0; e < 2; ++e) {
        int pp = wid * 2 + e;
#pragma unroll
        for (int bf = 0; bf < 2; ++bf) {
            int bcol = bf * 16 + (lane & 15);
            float bgv = bgs[bcol * 16 + pp];
#pragma unroll
            for (int r = 0; r < 4; ++r) {
                int m = (lane >> 4) * 4 + r;
                float invn = 1.f / fmaxf(csum_s[m * 16 + pp], 1e-12f);
                float v = fmaxf(logf(acc[e][bf][r] * invn * 0.4f + 1e-10f), bgv);
                atomicAdd(&pms[m * 32 + bcol], v);
            }
        }
    }
    __syncthreads();
    {
        int m = tid >> 5, bcol = tid & 31;
        atomicAdd(&pm[(size_t)bcol * KM_ + mt * 16 + m], pms[m * 32 + bcol]);
    }
}

// ---- K5: scores -> mix_likeli -> softmax
__global__ __launch_bounds__(64) void final_kernel(const float* __restrict__ pm,
                                                   float* __restrict__ out_soft,
                                                   float* __restrict__ out_ml) {
    int b = threadIdx.x;
    if (b >= B_) return;
    float ml[12];
#pragma unroll
    for (int c = 0; c < 12; ++c) {
        float s = -1e30f;
#pragma unroll
        for (int j = 0; j < 4; ++j) s = fmaxf(s, pm[(size_t)b * KM_ + c * 4 + j]);
        ml[c] = s / (float)HW_;
    }
    float z[12], zs = 0.f;
#pragma unroll
    for (int c = 0; c < 12; ++c) {
        float e = fminf(fmaxf(ml[c] * 2.f, -88.7f), 88.7f);
        z[c] = expf(e); zs += z[c];
    }
#pragma unroll
    for (int c = 0; c < 12; ++c) {
        out_soft[(size_t)b * 12 + c] = z[c] / zs;
        out_ml[(size_t)b * 12 + c] = ml[c];
    }
}

extern "C" void kernel_launch(void* const* d_in, const int* in_sizes, int n_in,
                              void* d_out, int out_size, void* d_ws, size_t ws_size,
                              hipStream_t stream) {
    const float* vgg = (const float*)d_in[0];
    const float* cw  = (const float*)d_in[1];
    const float* mmp = (const float*)d_in[2];
    const float* cl  = (const float*)d_in[3];
    float* out = (float*)d_out;
    char* ws = (char*)d_ws;

    unsigned short* wn   = (unsigned short*)(ws);              // 524288 B
    float* ck            = (float*)(ws + 524288);              // 10240 B
    float* invn          = (float*)(ws + 534528);              // 401408 B
    float* pm            = (float*)(ws + 935936);              // 6144 B
    float* bgacc         = (float*)(ws + 942080);              // 100352*8*4 = 3211264 B
    unsigned short* xnt  = (unsigned short*)(ws + 4153344);    // 102760448 B
    const size_t ACT_OFF = 4153344 + 102760448;                // 106913792
    const size_t ACT_BYTES = (size_t)B_ * HW_ * KF_ * 2;       // 102760448

    int big_ws = (ws_size >= ACT_OFF + ACT_BYTES) ? 1 : 0;
    unsigned short* act = big_ws ? (unsigned short*)(ws + ACT_OFF)
                                 : (unsigned short*)(out + 384);

    hipMemsetAsync(pm, 0, (size_t)B_ * KM_ * sizeof(float), stream);
    hipMemsetAsync(bgacc, 0, (size_t)B_ * HW_ * 8 * sizeof(float), stream);
    prep_kernel<<<dim3(KF_ + NCL_), dim3(64), 0, stream>>>(cw, cl, wn, ck);
    xprep_kernel<<<dim3(49, 32), dim3(512), 0, stream>>>(vgg, xnt, invn, out + 384, big_ws);
    gemm_act_kernel<<<dim3(784, 4), dim3(256), 0, stream>>>(xnt, wn, invn, ck, act, bgacc);
    fg_kernel<<<dim3(196, 3), dim3(512), 0, stream>>>(act, mmp, bgacc, pm);
    final_kernel<<<1, 64, 0, stream>>>(pm, out, out + 384 + (size_t)B_ * C_ * HW_);
    if (!big_ws)
        hipMemcpyAsync(out + 384, vgg, (size_t)B_ * C_ * HW_ * sizeof(float),
                       hipMemcpyDeviceToDevice, stream);
}